// Round 8
// baseline (190.361 us; speedup 1.0000x reference)
//
#include <hip/hip_runtime.h>

#define HW 4096
#define PADF 33      // f32 row stride for Xf
#define PADU 136     // ushort row stride for A/Y tiles (272 B, 16B-aligned)
typedef unsigned short ushort;
typedef __attribute__((ext_vector_type(8))) short short8;
typedef __attribute__((ext_vector_type(4))) float f32x4;

__device__ __forceinline__ ushort bf_rne(float f) {
  unsigned u = __float_as_uint(f);
  unsigned r = (u + 0x7fffu + ((u >> 16) & 1u)) >> 16;
  return (ushort)r;
}
__device__ __forceinline__ void split2(float f, ushort& hi, ushort& lo) {
  ushort h = bf_rne(f);
  float hf = __uint_as_float((unsigned)h << 16);
  hi = h;
  lo = bf_rne(f - hf);
}

// ---------------- prep: fold BN into pw weights, split everything to bf16 hi/lo ----
// roles: 0-7 W0 fold, 8-15 W1 fold, 16-23 wvp^T, 24-31 wop^T, 32-33 wom^T
__global__ __launch_bounds__(256) void prep(
    const float* __restrict__ g1, const float* __restrict__ be1,
    const float* __restrict__ m1, const float* __restrict__ v1,
    const float* __restrict__ w0,
    const float* __restrict__ g2, const float* __restrict__ be2,
    const float* __restrict__ m2, const float* __restrict__ v2,
    const float* __restrict__ w1,
    const float* __restrict__ wvp, const float* __restrict__ wom,
    const float* __restrict__ wop,
    ushort* __restrict__ W0h, ushort* __restrict__ W0l, float* __restrict__ b0,
    ushort* __restrict__ W1h, ushort* __restrict__ W1l, float* __restrict__ b1,
    ushort* __restrict__ vph, ushort* __restrict__ vpl,
    ushort* __restrict__ oph, ushort* __restrict__ opl,
    ushort* __restrict__ omh, ushort* __restrict__ oml)
{
  const int t = threadIdx.x;
  const int role = blockIdx.x;
  if (role < 16) {
    __shared__ float sc[128], sh[128], part[16][17];
    const int cv = role >> 3;
    const float* g  = cv ? g2 : g1;
    const float* be = cv ? be2 : be1;
    const float* mm = cv ? m2 : m1;
    const float* vv = cv ? v2 : v1;
    if (t < 128) {
      float s = g[t] / sqrtf(vv[t] + 1e-5f);
      sc[t] = s;
      sh[t] = be[t] - mm[t] * s;
    }
    __syncthreads();
    const float* ws = cv ? w1 : w0;
    ushort* dh = cv ? W1h : W0h;
    ushort* dl = cv ? W1l : W0l;
    float* bb  = cv ? b1 : b0;
    const int o = ((role & 7) << 4) + (t >> 4);
    const int kl = t & 15;
    float accb = 0.f;
    #pragma unroll
    for (int j = 0; j < 8; ++j) {
      const int k = (kl << 3) + j;
      const float wv = ws[o * 128 + k];
      ushort hi, lo;
      split2(wv * sc[k], hi, lo);
      dh[o * 128 + k] = hi;
      dl[o * 128 + k] = lo;
      accb = fmaf(wv, sh[k], accb);
    }
    part[t >> 4][kl] = accb;
    __syncthreads();
    if (kl == 0) {
      float s = 0.f;
      #pragma unroll
      for (int j = 0; j < 16; ++j) s += part[t >> 4][j];
      bb[o] = s;
    }
  } else if (role < 32) {
    const int rr = role & 7;
    const float* srcM = (role < 24) ? wvp : wop;
    ushort* dh = (role < 24) ? vph : oph;
    ushort* dl = (role < 24) ? vpl : opl;
    const int n = (rr << 4) + (t >> 4);
    const int kl = t & 15;
    #pragma unroll
    for (int j = 0; j < 8; ++j) {
      const int k = (kl << 3) + j;
      ushort hi, lo;
      split2(srcM[k * 128 + n], hi, lo);
      dh[n * 128 + k] = hi;
      dl[n * 128 + k] = lo;
    }
  } else {
    const int n = ((role - 32) << 4) + (t >> 4);   // 0..31
    const int kl = t & 15;
    #pragma unroll
    for (int j = 0; j < 8; ++j) {
      const int k = (kl << 3) + j;
      ushort hi, lo;
      split2(wom[k * 32 + n], hi, lo);
      omh[n * 128 + k] = hi;
      oml[n * 128 + k] = lo;
    }
  }
}

// ---------------- F1: x -(W0',b0)-> y2 tile -(reshape)-> tokens -(wvp|wom)-> value,om
// grid (32, 8), 512 thr (8 waves). Token r = o*32+cb, feature k = hw - cb*128.
__global__ __launch_bounds__(512, 2) void fused_x_valom(
    const float* __restrict__ x,
    const ushort* __restrict__ W0h, const ushort* __restrict__ W0l,
    const float* __restrict__ b0,
    const ushort* __restrict__ vph, const ushort* __restrict__ vpl,
    const float* __restrict__ bvp, const float* __restrict__ bom,
    float* __restrict__ value, float* __restrict__ omb)
{
  __shared__ __align__(16) char smem[102912];
  __shared__ float b0_s[128], b2_s[160];
  ushort (*Wh_s)[32] = (ushort(*)[32])(smem);
  ushort (*Wl_s)[32] = (ushort(*)[32])(smem + 8192);
  float*  Xf         = (float*)(smem + 16384);
  ushort (*Vh_s)[32] = (ushort(*)[32])(smem);
  ushort (*Vl_s)[32] = (ushort(*)[32])(smem + 10240);
  ushort (*Yh)[PADU] = (ushort(*)[PADU])(smem + 33280);
  ushort (*Yl)[PADU] = (ushort(*)[PADU])(smem + 68096);

  const int t = threadIdx.x;
  const int cb = blockIdx.x;
  const int b = blockIdx.y;
  const int hwBase = cb << 7;
  const size_t xbase = (size_t)b * (size_t)(128 * HW);
  if (t < 128) b0_s[t] = b0[t];
  if (t < 160) b2_s[t] = (t < 128) ? bvp[t] : bom[t - 128];
  const int lane = t & 63, w = t >> 6;
  const int col = lane & 15, quad = lane >> 4;
  const f32x4 z = {0.f, 0.f, 0.f, 0.f};

  // ---- phase 1: C[o=128][j=128]; wave w owns j-strip [w*16, w*16+16) ----
  f32x4 acc1[8];
  #pragma unroll
  for (int f = 0; f < 8; ++f) acc1[f] = z;

  for (int kc = 0; kc < 4; ++kc) {
    const int kB = kc << 5;
    {
      const int o = t >> 2, q8 = (t & 3) << 3;
      *(uint4*)&Wh_s[o][q8] = *(const uint4*)&W0h[o * 128 + kB + q8];
      *(uint4*)&Wl_s[o][q8] = *(const uint4*)&W0l[o * 128 + kB + q8];
    }
    #pragma unroll
    for (int p = 0; p < 2; ++p) {
      const int idx = (p << 9) + t;
      const int c = idx >> 5, j4 = (idx & 31) << 2;
      const float4 f = *(const float4*)&x[xbase + (size_t)(kB + c) * HW + hwBase + j4];
      Xf[(j4 + 0) * PADF + c] = f.x;
      Xf[(j4 + 1) * PADF + c] = f.y;
      Xf[(j4 + 2) * PADF + c] = f.z;
      Xf[(j4 + 3) * PADF + c] = f.w;
    }
    __syncthreads();
    union { ushort u[8]; short8 v; } bh, bl;
    {
      const float* xr = &Xf[((w << 4) + col) * PADF + (quad << 3)];
      #pragma unroll
      for (int j = 0; j < 8; ++j) split2(xr[j], bh.u[j], bl.u[j]);
    }
    #pragma unroll
    for (int f = 0; f < 8; ++f) {
      const int row = (f << 4) + col;
      const short8 aH = *(const short8*)&Wh_s[row][quad << 3];
      const short8 aL = *(const short8*)&Wl_s[row][quad << 3];
      acc1[f] = __builtin_amdgcn_mfma_f32_16x16x32_bf16(aH, bh.v, acc1[f], 0, 0, 0);
      acc1[f] = __builtin_amdgcn_mfma_f32_16x16x32_bf16(aH, bl.v, acc1[f], 0, 0, 0);
      acc1[f] = __builtin_amdgcn_mfma_f32_16x16x32_bf16(aL, bh.v, acc1[f], 0, 0, 0);
    }
    __syncthreads();
  }

  // scatter y2 (+bias) pre-split into Yh/Yl[token o][feature j]
  #pragma unroll
  for (int f = 0; f < 8; ++f)
    #pragma unroll
    for (int r = 0; r < 4; ++r) {
      const int o = (f << 4) + (quad << 2) + r;
      const int j = (w << 4) + col;
      ushort hi, lo;
      split2(acc1[f][r] + b0_s[o], hi, lo);
      Yh[o][j] = hi;
      Yl[o][j] = lo;
    }

  // ---- phase 2: [value|om][m=128 tokens][n=160]; waves: 4 m-strips x 2 n-halves ----
  const int wm2 = (w & 3) << 5;
  const int wn2 = (w >> 2) * 80;
  f32x4 acc2[2][5];
  #pragma unroll
  for (int i = 0; i < 2; ++i)
    #pragma unroll
    for (int j = 0; j < 5; ++j) acc2[i][j] = z;

  for (int j2 = 0; j2 < 4; ++j2) {
    for (int i = t; i < 640; i += 512) {
      const int n = i >> 2, q8 = (i & 3) << 3;
      *(uint4*)&Vh_s[n][q8] = *(const uint4*)&vph[n * 128 + (j2 << 5) + q8];
      *(uint4*)&Vl_s[n][q8] = *(const uint4*)&vpl[n * 128 + (j2 << 5) + q8];
    }
    __syncthreads();
    short8 aH[2], aL[2];
    #pragma unroll
    for (int f2 = 0; f2 < 2; ++f2) {
      const int row = wm2 + (f2 << 4) + col;
      aH[f2] = *(const short8*)&Yh[row][(j2 << 5) + (quad << 3)];
      aL[f2] = *(const short8*)&Yl[row][(j2 << 5) + (quad << 3)];
    }
    #pragma unroll
    for (int g2 = 0; g2 < 5; ++g2) {
      const int n = wn2 + (g2 << 4) + col;
      const short8 vh = *(const short8*)&Vh_s[n][quad << 3];
      const short8 vl = *(const short8*)&Vl_s[n][quad << 3];
      #pragma unroll
      for (int f2 = 0; f2 < 2; ++f2) {
        acc2[f2][g2] = __builtin_amdgcn_mfma_f32_16x16x32_bf16(aH[f2], vh, acc2[f2][g2], 0, 0, 0);
        acc2[f2][g2] = __builtin_amdgcn_mfma_f32_16x16x32_bf16(aH[f2], vl, acc2[f2][g2], 0, 0, 0);
        acc2[f2][g2] = __builtin_amdgcn_mfma_f32_16x16x32_bf16(aL[f2], vh, acc2[f2][g2], 0, 0, 0);
      }
    }
    __syncthreads();
  }
  #pragma unroll
  for (int f2 = 0; f2 < 2; ++f2)
    #pragma unroll
    for (int r = 0; r < 4; ++r) {
      const int m = wm2 + (f2 << 4) + (quad << 2) + r;
      const size_t gRow = (size_t)b * HW + (size_t)m * 32 + cb;
      #pragma unroll
      for (int g2 = 0; g2 < 5; ++g2) {
        const int n = wn2 + (g2 << 4) + col;
        const float v = acc2[f2][g2][r] + b2_s[n];
        if (n < 128) value[gRow * 128 + n] = v;
        else         omb[gRow * 32 + (n - 128)] = v;
      }
    }
}

// ---------------- F2': gather(value,om) -> samp regs -> (wop) -> xnew -> (W1',b1) -> out
// grid (256): b = blk&7 (XCD affinity, value slab 2MB/batch stays in one L2), cb = blk>>3.
// 512 thr. Tokens {tk*32+cb}. Gather: thread = (token tk = t>>2, ch quarter q = t&3).
__global__ __launch_bounds__(512, 2) void fused_samp_op_out(
    const float* __restrict__ value, const float* __restrict__ omb,
    const ushort* __restrict__ oph, const ushort* __restrict__ opl,
    const ushort* __restrict__ W1h, const ushort* __restrict__ W1l,
    const float* __restrict__ b1, float* __restrict__ out)
{
  // regionA @0: Ah[128][136] (34816) + Al @34816  — aliased by Yh/Yl in phase 2
  // regionB @69632 (16896 B): oms[128][33] f32 | {Bh,Bl}[128][32] | {W1h_s,W1l_s}
  __shared__ __align__(16) char smem[86528];
  __shared__ float b1_s[128];
  ushort (*Ah_s)[PADU] = (ushort(*)[PADU])(smem);
  ushort (*Al_s)[PADU] = (ushort(*)[PADU])(smem + 34816);
  float  (*oms)[33]    = (float(*)[33])(smem + 69632);
  ushort (*Bh_s)[32]   = (ushort(*)[32])(smem + 69632);
  ushort (*Bl_s)[32]   = (ushort(*)[32])(smem + 77824);
  ushort (*W1h_s)[32]  = (ushort(*)[32])(smem + 69632);
  ushort (*W1l_s)[32]  = (ushort(*)[32])(smem + 77824);
  ushort (*Yh)[PADU]   = (ushort(*)[PADU])(smem);
  ushort (*Yl)[PADU]   = (ushort(*)[PADU])(smem + 34816);

  const int t = threadIdx.x;
  const int blk = blockIdx.x;
  const int b = blk & 7;
  const int cb = blk >> 3;
  if (t < 128) b1_s[t] = b1[t];
  const int lane = t & 63, w = t >> 6;
  const int col = lane & 15, quad = lane >> 4;
  const f32x4 z = {0.f, 0.f, 0.f, 0.f};

  // ---- phase 0: stage om rows, then bilinear gather into registers ----
  {
    const int tk0 = t >> 2, jo = (t & 3) << 3;
    const float* orow = &omb[((size_t)b * HW + (size_t)tk0 * 32 + cb) * 32 + jo];
    *(float4*)&oms[tk0][jo]     = *(const float4*)orow;
    *(float4*)&oms[tk0][jo + 4] = *(const float4*)(orow + 4);
  }
  __syncthreads();
  const int tk = t >> 2, q = t & 3;
  const int s = tk * 32 + cb;
  const int h = s >> 6, wq = s & 63;
  const float* vb = value + (size_t)b * HW * 128 + (q << 5);
  const float* omp = oms[tk];
  const float fw = (float)wq, fh = (float)h;
  float acc[32];
  #pragma unroll
  for (int j = 0; j < 32; ++j) acc[j] = 0.f;
  for (int k = 0; k < 9; ++k) {
    const float kx = (float)(k % 3 - 1);
    const float ky = (float)(k / 3 - 1);
    const float dx = omp[k * 3 + 0];
    const float dy = omp[k * 3 + 1];
    const float m  = omp[k * 3 + 2];
    const float px = fw + kx + dx;
    const float py = fh + ky + dy;
    const float x0f = floorf(px), y0f = floorf(py);
    const float fx = px - x0f, fy = py - y0f;
    const int ix = (int)x0f, iy = (int)y0f;
    #pragma unroll
    for (int cy = 0; cy < 2; ++cy) {
      const int yi = iy + cy;
      const float wy = cy ? fy : 1.f - fy;
      const float vy = (yi >= 0 && yi < 64) ? 1.f : 0.f;
      const int yc = min(max(yi, 0), 63);
      #pragma unroll
      for (int cx = 0; cx < 2; ++cx) {
        const int xi = ix + cx;
        const float wx = cx ? fx : 1.f - fx;
        const float vx = (xi >= 0 && xi < 64) ? 1.f : 0.f;
        const int xc = min(max(xi, 0), 63);
        const float wgt = wx * wy * vx * vy * m;
        const float* src = vb + (size_t)(yc * 64 + xc) * 128;
        #pragma unroll
        for (int c4 = 0; c4 < 8; ++c4) {
          const float4 v = *(const float4*)(src + (c4 << 2));
          acc[c4 * 4 + 0] = fmaf(wgt, v.x, acc[c4 * 4 + 0]);
          acc[c4 * 4 + 1] = fmaf(wgt, v.y, acc[c4 * 4 + 1]);
          acc[c4 * 4 + 2] = fmaf(wgt, v.z, acc[c4 * 4 + 2]);
          acc[c4 * 4 + 3] = fmaf(wgt, v.w, acc[c4 * 4 + 3]);
        }
      }
    }
  }
  // scatter samp pre-split into A tile [token][k=cg]
  #pragma unroll
  for (int j = 0; j < 32; ++j) {
    ushort hi, lo;
    split2(acc[j], hi, lo);
    Ah_s[tk][(q << 5) + j] = hi;
    Al_s[tk][(q << 5) + j] = lo;
  }
  __syncthreads();

  // ---- phase 1: C[ch=128][j=128] = samp * wop'; waves: 2 m-halves x 4 n-strips ----
  const int wm1 = (w & 1) << 6, wn1 = (w >> 1) << 5;
  f32x4 acc1[4][2];
  #pragma unroll
  for (int i = 0; i < 4; ++i) { acc1[i][0] = z; acc1[i][1] = z; }

  for (int kc = 0; kc < 4; ++kc) {
    const int kB = kc << 5;
    {
      const int n = t >> 2, q8 = (t & 3) << 3;
      *(uint4*)&Bh_s[n][q8] = *(const uint4*)&oph[n * 128 + kB + q8];
      *(uint4*)&Bl_s[n][q8] = *(const uint4*)&opl[n * 128 + kB + q8];
    }
    __syncthreads();
    short8 aH[4], aL[4];
    #pragma unroll
    for (int f = 0; f < 4; ++f) {
      const int row = wm1 + (f << 4) + col;
      aH[f] = *(const short8*)&Ah_s[row][kB + (quad << 3)];
      aL[f] = *(const short8*)&Al_s[row][kB + (quad << 3)];
    }
    #pragma unroll
    for (int g = 0; g < 2; ++g) {
      const int n = wn1 + (g << 4) + col;
      const short8 bh = *(const short8*)&Bh_s[n][quad << 3];
      const short8 bl = *(const short8*)&Bl_s[n][quad << 3];
      #pragma unroll
      for (int f = 0; f < 4; ++f) {
        acc1[f][g] = __builtin_amdgcn_mfma_f32_16x16x32_bf16(aH[f], bh, acc1[f][g], 0, 0, 0);
        acc1[f][g] = __builtin_amdgcn_mfma_f32_16x16x32_bf16(aH[f], bl, acc1[f][g], 0, 0, 0);
        acc1[f][g] = __builtin_amdgcn_mfma_f32_16x16x32_bf16(aL[f], bh, acc1[f][g], 0, 0, 0);
      }
    }
    __syncthreads();
  }

  // scatter xnew pre-split into Yh/Yl[j][ch]  (aliases A region; A dead)
  #pragma unroll
  for (int f = 0; f < 4; ++f)
    #pragma unroll
    for (int g = 0; g < 2; ++g)
      #pragma unroll
      for (int r = 0; r < 4; ++r) {
        const int ch = wm1 + (f << 4) + (quad << 2) + r;
        const int j  = wn1 + (g << 4) + col;
        ushort hi, lo;
        split2(acc1[f][g][r], hi, lo);
        Yh[j][ch] = hi;
        Yl[j][ch] = lo;
      }

  // ---- phase 2: out[o=128][j=128] = W1'[o][ch] * xnew[ch][j] ----
  const int wm2 = (w & 1) << 6, wn2 = (w >> 1) << 5;
  f32x4 acc2[4][2];
  #pragma unroll
  for (int i = 0; i < 4; ++i) { acc2[i][0] = z; acc2[i][1] = z; }

  for (int j2 = 0; j2 < 4; ++j2) {
    {
      const int o = t >> 2, q8 = (t & 3) << 3;
      *(uint4*)&W1h_s[o][q8] = *(const uint4*)&W1h[o * 128 + (j2 << 5) + q8];
      *(uint4*)&W1l_s[o][q8] = *(const uint4*)&W1l[o * 128 + (j2 << 5) + q8];
    }
    __syncthreads();
    short8 aH[4], aL[4];
    #pragma unroll
    for (int f2 = 0; f2 < 4; ++f2) {
      const int row = wm2 + (f2 << 4) + col;
      aH[f2] = *(const short8*)&W1h_s[row][quad << 3];
      aL[f2] = *(const short8*)&W1l_s[row][quad << 3];
    }
    #pragma unroll
    for (int g2 = 0; g2 < 2; ++g2) {
      const int j = wn2 + (g2 << 4) + col;
      const short8 bh = *(const short8*)&Yh[j][(j2 << 5) + (quad << 3)];
      const short8 bl = *(const short8*)&Yl[j][(j2 << 5) + (quad << 3)];
      #pragma unroll
      for (int f2 = 0; f2 < 4; ++f2) {
        acc2[f2][g2] = __builtin_amdgcn_mfma_f32_16x16x32_bf16(aH[f2], bh, acc2[f2][g2], 0, 0, 0);
        acc2[f2][g2] = __builtin_amdgcn_mfma_f32_16x16x32_bf16(aH[f2], bl, acc2[f2][g2], 0, 0, 0);
        acc2[f2][g2] = __builtin_amdgcn_mfma_f32_16x16x32_bf16(aL[f2], bh, acc2[f2][g2], 0, 0, 0);
      }
    }
    __syncthreads();
  }
  const size_t obase = (size_t)b * (size_t)(128 * HW) + ((size_t)cb << 7);
  #pragma unroll
  for (int f2 = 0; f2 < 4; ++f2)
    #pragma unroll
    for (int r = 0; r < 4; ++r) {
      const int o = wm2 + (f2 << 4) + (quad << 2) + r;
      #pragma unroll
      for (int g2 = 0; g2 < 2; ++g2) {
        const int j = wn2 + (g2 << 4) + col;
        out[obase + (size_t)o * HW + j] = acc2[f2][g2][r] + b1_s[o];
      }
    }
}

extern "C" void kernel_launch(void* const* d_in, const int* in_sizes, int n_in,
                              void* d_out, int out_size, void* d_ws, size_t ws_size,
                              hipStream_t stream)
{
  const float* x    = (const float*)d_in[0];
  const float* g1   = (const float*)d_in[1];
  const float* be1  = (const float*)d_in[2];
  const float* m1   = (const float*)d_in[3];
  const float* v1   = (const float*)d_in[4];
  const float* wpw0 = (const float*)d_in[5];
  const float* wvp  = (const float*)d_in[6];
  const float* bvp  = (const float*)d_in[7];
  const float* womW = (const float*)d_in[8];
  const float* bom  = (const float*)d_in[9];
  const float* wop  = (const float*)d_in[10];
  const float* g2   = (const float*)d_in[11];
  const float* be2  = (const float*)d_in[12];
  const float* m2   = (const float*)d_in[13];
  const float* v2   = (const float*)d_in[14];
  const float* wpw1 = (const float*)d_in[15];

  char* ws = (char*)d_ws;
  float*  value = (float*) (ws + 0);          // 16 MB (b,s,cg) f32
  float*  omb   = (float*) (ws + 16777216);   //  4 MB (b,s,32) f32
  size_t o = 20971520;
  ushort* W0h = (ushort*)(ws + o); o += 32768;
  ushort* W0l = (ushort*)(ws + o); o += 32768;
  ushort* W1h = (ushort*)(ws + o); o += 32768;
  ushort* W1l = (ushort*)(ws + o); o += 32768;
  ushort* vph = (ushort*)(ws + o); o += 40960;  // 160 x 128 (value 128 rows + om 32 rows)
  ushort* vpl = (ushort*)(ws + o); o += 40960;
  ushort* oph = (ushort*)(ws + o); o += 32768;
  ushort* opl = (ushort*)(ws + o); o += 32768;
  float*  b0  = (float*)(ws + o);  o += 512;
  float*  b1  = (float*)(ws + o);
  ushort* omh = vph + 128 * 128;   // om rows live at n = 128..159 of the V matrix
  ushort* oml = vpl + 128 * 128;

  prep<<<34, 256, 0, stream>>>(g1, be1, m1, v1, wpw0, g2, be2, m2, v2, wpw1,
                               wvp, womW, wop,
                               W0h, W0l, b0, W1h, W1l, b1,
                               vph, vpl, oph, opl, omh, oml);
  fused_x_valom<<<dim3(32, 8), 512, 0, stream>>>(x, W0h, W0l, b0, vph, vpl,
                                                 bvp, bom, value, omb);
  fused_samp_op_out<<<dim3(256), 512, 0, stream>>>(value, omb, oph, opl,
                                                   W1h, W1l, b1, (float*)d_out);
}

// Round 9
// 148.637 us; speedup vs baseline: 1.2807x; 1.2807x over previous
//
#include <hip/hip_runtime.h>

#define HW 4096
#define PADF 33      // f32 row stride for Xf
#define PADU 136     // ushort row stride for Y tiles (272 B, 16B-aligned)
typedef unsigned short ushort;
typedef __attribute__((ext_vector_type(8))) short short8;
typedef __attribute__((ext_vector_type(4))) float f32x4;

__device__ __forceinline__ ushort bf_rne(float f) {
  unsigned u = __float_as_uint(f);
  unsigned r = (u + 0x7fffu + ((u >> 16) & 1u)) >> 16;
  return (ushort)r;
}
__device__ __forceinline__ void split2(float f, ushort& hi, ushort& lo) {
  ushort h = bf_rne(f);
  float hf = __uint_as_float((unsigned)h << 16);
  hi = h;
  lo = bf_rne(f - hf);
}

// ---------------- prep: fold BN into pw weights, split everything to bf16 hi/lo ----
__global__ __launch_bounds__(256) void prep(
    const float* __restrict__ g1, const float* __restrict__ be1,
    const float* __restrict__ m1, const float* __restrict__ v1,
    const float* __restrict__ w0,
    const float* __restrict__ g2, const float* __restrict__ be2,
    const float* __restrict__ m2, const float* __restrict__ v2,
    const float* __restrict__ w1,
    const float* __restrict__ wvp, const float* __restrict__ wom,
    const float* __restrict__ wop,
    ushort* __restrict__ W0h, ushort* __restrict__ W0l, float* __restrict__ b0,
    ushort* __restrict__ W1h, ushort* __restrict__ W1l, float* __restrict__ b1,
    ushort* __restrict__ vph, ushort* __restrict__ vpl,
    ushort* __restrict__ oph, ushort* __restrict__ opl,
    ushort* __restrict__ omh, ushort* __restrict__ oml)
{
  const int t = threadIdx.x;
  const int role = blockIdx.x;
  if (role < 16) {
    __shared__ float sc[128], sh[128], part[16][17];
    const int cv = role >> 3;
    const float* g  = cv ? g2 : g1;
    const float* be = cv ? be2 : be1;
    const float* mm = cv ? m2 : m1;
    const float* vv = cv ? v2 : v1;
    if (t < 128) {
      float s = g[t] / sqrtf(vv[t] + 1e-5f);
      sc[t] = s;
      sh[t] = be[t] - mm[t] * s;
    }
    __syncthreads();
    const float* ws = cv ? w1 : w0;
    ushort* dh = cv ? W1h : W0h;
    ushort* dl = cv ? W1l : W0l;
    float* bb  = cv ? b1 : b0;
    const int o = ((role & 7) << 4) + (t >> 4);
    const int kl = t & 15;
    float accb = 0.f;
    #pragma unroll
    for (int j = 0; j < 8; ++j) {
      const int k = (kl << 3) + j;
      const float wv = ws[o * 128 + k];
      ushort hi, lo;
      split2(wv * sc[k], hi, lo);
      dh[o * 128 + k] = hi;
      dl[o * 128 + k] = lo;
      accb = fmaf(wv, sh[k], accb);
    }
    part[t >> 4][kl] = accb;
    __syncthreads();
    if (kl == 0) {
      float s = 0.f;
      #pragma unroll
      for (int j = 0; j < 16; ++j) s += part[t >> 4][j];
      bb[o] = s;
    }
  } else if (role < 32) {
    const int rr = role & 7;
    const float* srcM = (role < 24) ? wvp : wop;
    ushort* dh = (role < 24) ? vph : oph;
    ushort* dl = (role < 24) ? vpl : opl;
    const int n = (rr << 4) + (t >> 4);
    const int kl = t & 15;
    #pragma unroll
    for (int j = 0; j < 8; ++j) {
      const int k = (kl << 3) + j;
      ushort hi, lo;
      split2(srcM[k * 128 + n], hi, lo);
      dh[n * 128 + k] = hi;
      dl[n * 128 + k] = lo;
    }
  } else {
    const int n = ((role - 32) << 4) + (t >> 4);
    const int kl = t & 15;
    #pragma unroll
    for (int j = 0; j < 8; ++j) {
      const int k = (kl << 3) + j;
      ushort hi, lo;
      split2(wom[k * 32 + n], hi, lo);
      omh[n * 128 + k] = hi;
      oml[n * 128 + k] = lo;
    }
  }
}

// ---------------- F1: x -(W0',b0)-> y2 half-tile -> tokens -(wvp|wom)-> value,om ----
// grid (32 cb, 8 b, 2 oh), 256 thr. Block owns o in [oh*64, oh*64+64) => 64 tokens
// {(oBase+m)*32+cb}. LDS: Y region aliases dead phase-1 staging. ~56 KB -> 2 blk/CU.
__global__ __launch_bounds__(256, 2) void fused_x_valom(
    const float* __restrict__ x,
    const ushort* __restrict__ W0h, const ushort* __restrict__ W0l,
    const float* __restrict__ b0,
    const ushort* __restrict__ vph, const ushort* __restrict__ vpl,
    const float* __restrict__ bvp, const float* __restrict__ bom,
    float* __restrict__ value, float* __restrict__ omb)
{
  // P1: Wh@0(4096) Wl@4096 Xf@8192(16896) = 25088  [aliased by Y]
  // P2: Yh@0(17408) Yl@17408 | Vh@34816(10240) Vl@45056(10240) = 55296
  __shared__ __align__(16) char smem[55296];
  __shared__ float b0_s[64], b2_s[160];
  ushort (*Wh_s)[32] = (ushort(*)[32])(smem);
  ushort (*Wl_s)[32] = (ushort(*)[32])(smem + 4096);
  float*  Xf         = (float*)(smem + 8192);
  ushort (*Yh)[PADU] = (ushort(*)[PADU])(smem);
  ushort (*Yl)[PADU] = (ushort(*)[PADU])(smem + 17408);
  ushort (*Vh_s)[32] = (ushort(*)[32])(smem + 34816);
  ushort (*Vl_s)[32] = (ushort(*)[32])(smem + 45056);

  const int t = threadIdx.x;
  const int cb = blockIdx.x;
  const int b  = blockIdx.y;
  const int oBase = blockIdx.z << 6;
  const int hwBase = cb << 7;
  const size_t xbase = (size_t)b * (size_t)(128 * HW);
  if (t < 64)  b0_s[t] = b0[oBase + t];
  if (t < 160) b2_s[t] = (t < 128) ? bvp[t] : bom[t - 128];
  const int lane = t & 63, w = t >> 6;          // 4 waves
  const int col = lane & 15, quad = lane >> 4;
  const f32x4 z = {0.f, 0.f, 0.f, 0.f};

  // ---- phase 1: C[o=64][j=128]; wave w owns j-strip [w*32, w*32+32) ----
  f32x4 acc1[4][2];
  #pragma unroll
  for (int i = 0; i < 4; ++i) { acc1[i][0] = z; acc1[i][1] = z; }

  for (int kc = 0; kc < 4; ++kc) {
    const int kB = kc << 5;
    {
      const int o = t >> 2, q8 = (t & 3) << 3;
      *(uint4*)&Wh_s[o][q8] = *(const uint4*)&W0h[(oBase + o) * 128 + kB + q8];
      *(uint4*)&Wl_s[o][q8] = *(const uint4*)&W0l[(oBase + o) * 128 + kB + q8];
    }
    #pragma unroll
    for (int p = 0; p < 4; ++p) {
      const int idx = (p << 8) + t;
      const int c = idx >> 5, j4 = (idx & 31) << 2;
      const float4 f = *(const float4*)&x[xbase + (size_t)(kB + c) * HW + hwBase + j4];
      Xf[(j4 + 0) * PADF + c] = f.x;
      Xf[(j4 + 1) * PADF + c] = f.y;
      Xf[(j4 + 2) * PADF + c] = f.z;
      Xf[(j4 + 3) * PADF + c] = f.w;
    }
    __syncthreads();
    union { ushort u[8]; short8 v; } bh[2], bl[2];
    #pragma unroll
    for (int g = 0; g < 2; ++g) {
      const float* xr = &Xf[((w << 5) + (g << 4) + col) * PADF + (quad << 3)];
      #pragma unroll
      for (int j = 0; j < 8; ++j) split2(xr[j], bh[g].u[j], bl[g].u[j]);
    }
    #pragma unroll
    for (int f = 0; f < 4; ++f) {
      const int row = (f << 4) + col;
      const short8 aH = *(const short8*)&Wh_s[row][quad << 3];
      const short8 aL = *(const short8*)&Wl_s[row][quad << 3];
      #pragma unroll
      for (int g = 0; g < 2; ++g) {
        acc1[f][g] = __builtin_amdgcn_mfma_f32_16x16x32_bf16(aH, bh[g].v, acc1[f][g], 0, 0, 0);
        acc1[f][g] = __builtin_amdgcn_mfma_f32_16x16x32_bf16(aH, bl[g].v, acc1[f][g], 0, 0, 0);
        acc1[f][g] = __builtin_amdgcn_mfma_f32_16x16x32_bf16(aL, bh[g].v, acc1[f][g], 0, 0, 0);
      }
    }
    __syncthreads();
  }

  // scatter y2 (+bias) pre-split into Yh/Yl[token m][feature j]  (P1 staging dead)
  #pragma unroll
  for (int f = 0; f < 4; ++f)
    #pragma unroll
    for (int r = 0; r < 4; ++r) {
      const int m = (f << 4) + (quad << 2) + r;
      #pragma unroll
      for (int g = 0; g < 2; ++g) {
        const int j = (w << 5) + (g << 4) + col;
        ushort hi, lo;
        split2(acc1[f][g][r] + b0_s[m], hi, lo);
        Yh[m][j] = hi;
        Yl[m][j] = lo;
      }
    }

  // ---- phase 2: [value|om][m=64][n=160]; waves: 2 m-strips x 2 n-halves ----
  const int wm2 = (w & 1) << 5;
  const int wn2 = (w >> 1) * 80;
  f32x4 acc2[2][5];
  #pragma unroll
  for (int i = 0; i < 2; ++i)
    #pragma unroll
    for (int j = 0; j < 5; ++j) acc2[i][j] = z;

  for (int j2 = 0; j2 < 4; ++j2) {
    for (int i = t; i < 640; i += 256) {
      const int n = i >> 2, q8 = (i & 3) << 3;
      *(uint4*)&Vh_s[n][q8] = *(const uint4*)&vph[n * 128 + (j2 << 5) + q8];
      *(uint4*)&Vl_s[n][q8] = *(const uint4*)&vpl[n * 128 + (j2 << 5) + q8];
    }
    __syncthreads();
    short8 aH[2], aL[2];
    #pragma unroll
    for (int f2 = 0; f2 < 2; ++f2) {
      const int row = wm2 + (f2 << 4) + col;
      aH[f2] = *(const short8*)&Yh[row][(j2 << 5) + (quad << 3)];
      aL[f2] = *(const short8*)&Yl[row][(j2 << 5) + (quad << 3)];
    }
    #pragma unroll
    for (int g2 = 0; g2 < 5; ++g2) {
      const int n = wn2 + (g2 << 4) + col;
      const short8 vh = *(const short8*)&Vh_s[n][quad << 3];
      const short8 vl = *(const short8*)&Vl_s[n][quad << 3];
      #pragma unroll
      for (int f2 = 0; f2 < 2; ++f2) {
        acc2[f2][g2] = __builtin_amdgcn_mfma_f32_16x16x32_bf16(aH[f2], vh, acc2[f2][g2], 0, 0, 0);
        acc2[f2][g2] = __builtin_amdgcn_mfma_f32_16x16x32_bf16(aH[f2], vl, acc2[f2][g2], 0, 0, 0);
        acc2[f2][g2] = __builtin_amdgcn_mfma_f32_16x16x32_bf16(aL[f2], vh, acc2[f2][g2], 0, 0, 0);
      }
    }
    __syncthreads();
  }
  #pragma unroll
  for (int f2 = 0; f2 < 2; ++f2)
    #pragma unroll
    for (int r = 0; r < 4; ++r) {
      const int m = wm2 + (f2 << 4) + (quad << 2) + r;
      const size_t gRow = (size_t)b * HW + (size_t)(oBase + m) * 32 + cb;
      #pragma unroll
      for (int g2 = 0; g2 < 5; ++g2) {
        const int n = wn2 + (g2 << 4) + col;
        const float v = acc2[f2][g2][r] + b2_s[n];
        if (n < 128) value[gRow * 128 + n] = v;
        else         omb[gRow * 32 + (n - 128)] = v;
      }
    }
}

// ---------------- deformable bilinear sampling -> pre-split bf16 hi/lo ----------------
// b = blk&7: batch<->XCD affinity; 8 consecutive s per block (window locality).
__global__ __launch_bounds__(256) void dcn_sample(
    const float* __restrict__ value, const float* __restrict__ om,
    ushort* __restrict__ samph, ushort* __restrict__ sampl)
{
  __shared__ float oms[8][32];
  const int t = threadIdx.x;
  const int blk = blockIdx.x;
  const int b = blk & 7;
  const int sBase = (blk >> 3) << 3;
  const int s = sBase + (t >> 5);
  const int cg = (t & 31) << 2;
  oms[t >> 5][t & 31] = om[((size_t)b * HW + sBase + (t >> 5)) * 32 + (t & 31)];
  __syncthreads();
  const int h = s >> 6, wq = s & 63;
  const float* vb = value + (size_t)b * HW * 128;
  const float* omp = oms[t >> 5];
  const float fw = (float)wq, fh = (float)h;
  float4 acc = {0.f, 0.f, 0.f, 0.f};
  #pragma unroll
  for (int k = 0; k < 9; ++k) {
    const float kx = (float)(k % 3 - 1);
    const float ky = (float)(k / 3 - 1);
    const float dx = omp[k * 3 + 0];
    const float dy = omp[k * 3 + 1];
    const float m  = omp[k * 3 + 2];
    const float px = fw + kx + dx;
    const float py = fh + ky + dy;
    const float x0f = floorf(px), y0f = floorf(py);
    const float fx = px - x0f, fy = py - y0f;
    const int ix = (int)x0f, iy = (int)y0f;
    #pragma unroll
    for (int cy = 0; cy < 2; ++cy) {
      const int yi = iy + cy;
      const float wy = cy ? fy : 1.f - fy;
      const float vy = (yi >= 0 && yi < 64) ? 1.f : 0.f;
      const int yc = min(max(yi, 0), 63);
      #pragma unroll
      for (int cx = 0; cx < 2; ++cx) {
        const int xi = ix + cx;
        const float wx = cx ? fx : 1.f - fx;
        const float vx = (xi >= 0 && xi < 64) ? 1.f : 0.f;
        const int xc = min(max(xi, 0), 63);
        const float wgt = wx * wy * vx * vy * m;
        const float4 v = *(const float4*)&vb[(size_t)(yc * 64 + xc) * 128 + cg];
        acc.x = fmaf(wgt, v.x, acc.x);
        acc.y = fmaf(wgt, v.y, acc.y);
        acc.z = fmaf(wgt, v.z, acc.z);
        acc.w = fmaf(wgt, v.w, acc.w);
      }
    }
  }
  ushort h0, l0, h1, l1, h2, l2, h3, l3;
  split2(acc.x, h0, l0); split2(acc.y, h1, l1);
  split2(acc.z, h2, l2); split2(acc.w, h3, l3);
  const size_t idx = ((size_t)b * HW + s) * 128 + cg;
  uint2 uh, ul;
  uh.x = (unsigned)h0 | ((unsigned)h1 << 16);
  uh.y = (unsigned)h2 | ((unsigned)h3 << 16);
  ul.x = (unsigned)l0 | ((unsigned)l1 << 16);
  ul.y = (unsigned)l2 | ((unsigned)l3 << 16);
  *(uint2*)&samph[idx] = uh;
  *(uint2*)&sampl[idx] = ul;
}

// ---------------- F2: samp rows {m*32+cb} -(wop)-> xnew[ch][j half] -(W1',b1)-> out ----
// grid (64, 8): cb = x&31, jh = x>>5. 256 thr. ~51 KB LDS -> 2-3 blk/CU.
__global__ __launch_bounds__(256, 2) void fused_op_out(
    const ushort* __restrict__ samph, const ushort* __restrict__ sampl,
    const ushort* __restrict__ oph, const ushort* __restrict__ opl,
    const ushort* __restrict__ W1h, const ushort* __restrict__ W1l,
    const float* __restrict__ b1, float* __restrict__ out)
{
  // P1: Ah@0(8192) Al@8192 Bh@16384(4096) Bl@20480 = 24576  [aliased by Y]
  // P2: Yh@0(17408) Yl@17408 | W1h_s@34816(8192) W1l_s@43008 = 51200
  __shared__ __align__(16) char smem[51200];
  __shared__ float b1_s[128];
  ushort (*Ah_s)[32]  = (ushort(*)[32])(smem);
  ushort (*Al_s)[32]  = (ushort(*)[32])(smem + 8192);
  ushort (*Bh_s)[32]  = (ushort(*)[32])(smem + 16384);
  ushort (*Bl_s)[32]  = (ushort(*)[32])(smem + 20480);
  ushort (*Yh)[PADU]  = (ushort(*)[PADU])(smem);
  ushort (*Yl)[PADU]  = (ushort(*)[PADU])(smem + 17408);
  ushort (*W1h_s)[32] = (ushort(*)[32])(smem + 34816);
  ushort (*W1l_s)[32] = (ushort(*)[32])(smem + 43008);

  const int t = threadIdx.x;
  const int cb = blockIdx.x & 31;
  const int jBase = (blockIdx.x >> 5) << 6;
  const int b = blockIdx.y;
  if (t < 128) b1_s[t] = b1[t];
  const int lane = t & 63, w = t >> 6;
  const int col = lane & 15, quad = lane >> 4;
  const f32x4 z = {0.f, 0.f, 0.f, 0.f};

  // ---- phase 1: C[ch=128][j=64]; waves: 2 m-halves x 2 n-strips ----
  const int wm1 = (w & 1) << 6, wn1 = (w >> 1) << 5;
  f32x4 acc1[4][2];
  #pragma unroll
  for (int i = 0; i < 4; ++i) { acc1[i][0] = z; acc1[i][1] = z; }

  for (int kc = 0; kc < 4; ++kc) {
    const int kB = kc << 5;
    for (int i = t; i < 512; i += 256) {
      const int m = i >> 2, q8 = (i & 3) << 3;
      const size_t row = (size_t)b * HW + (size_t)m * 32 + cb;
      *(uint4*)&Ah_s[m][q8] = *(const uint4*)&samph[row * 128 + kB + q8];
      *(uint4*)&Al_s[m][q8] = *(const uint4*)&sampl[row * 128 + kB + q8];
    }
    {
      const int n = t >> 2, q8 = (t & 3) << 3;
      *(uint4*)&Bh_s[n][q8] = *(const uint4*)&oph[(jBase + n) * 128 + kB + q8];
      *(uint4*)&Bl_s[n][q8] = *(const uint4*)&opl[(jBase + n) * 128 + kB + q8];
    }
    __syncthreads();
    short8 aH[4], aL[4];
    #pragma unroll
    for (int f = 0; f < 4; ++f) {
      const int row = wm1 + (f << 4) + col;
      aH[f] = *(const short8*)&Ah_s[row][quad << 3];
      aL[f] = *(const short8*)&Al_s[row][quad << 3];
    }
    #pragma unroll
    for (int g = 0; g < 2; ++g) {
      const int n = wn1 + (g << 4) + col;
      const short8 bh = *(const short8*)&Bh_s[n][quad << 3];
      const short8 bl = *(const short8*)&Bl_s[n][quad << 3];
      #pragma unroll
      for (int f = 0; f < 4; ++f) {
        acc1[f][g] = __builtin_amdgcn_mfma_f32_16x16x32_bf16(aH[f], bh, acc1[f][g], 0, 0, 0);
        acc1[f][g] = __builtin_amdgcn_mfma_f32_16x16x32_bf16(aH[f], bl, acc1[f][g], 0, 0, 0);
        acc1[f][g] = __builtin_amdgcn_mfma_f32_16x16x32_bf16(aL[f], bh, acc1[f][g], 0, 0, 0);
      }
    }
    __syncthreads();
  }

  // scatter xnew pre-split into Yh/Yl[j][ch]  (P1 staging dead)
  #pragma unroll
  for (int f = 0; f < 4; ++f)
    #pragma unroll
    for (int g = 0; g < 2; ++g)
      #pragma unroll
      for (int r = 0; r < 4; ++r) {
        const int ch = wm1 + (f << 4) + (quad << 2) + r;
        const int j  = wn1 + (g << 4) + col;
        ushort hi, lo;
        split2(acc1[f][g][r], hi, lo);
        Yh[j][ch] = hi;
        Yl[j][ch] = lo;
      }

  // ---- phase 2: out[o=128][j=64]; waves: 2 o-halves x 2 j-strips ----
  const int wm2 = (w & 1) << 6, wn2 = (w >> 1) << 5;
  f32x4 acc2[4][2];
  #pragma unroll
  for (int i = 0; i < 4; ++i) { acc2[i][0] = z; acc2[i][1] = z; }

  for (int j2 = 0; j2 < 4; ++j2) {
    for (int i = t; i < 512; i += 256) {
      const int o = i >> 2, q8 = (i & 3) << 3;
      *(uint4*)&W1h_s[o][q8] = *(const uint4*)&W1h[o * 128 + (j2 << 5) + q8];
      *(uint4*)&W1l_s[o][q8] = *(const uint4*)&W1l[o * 128 + (j2 << 5) + q8];
    }
    __syncthreads();
    short8 aH[4], aL[4];
    #pragma unroll
    for (int f2 = 0; f2 < 4; ++f2) {
      const int row = wm2 + (f2 << 4) + col;
      aH[f2] = *(const short8*)&W1h_s[row][quad << 3];
      aL[f2] = *(const short8*)&W1l_s[row][quad << 3];
    }
    #pragma unroll
    for (int g2 = 0; g2 < 2; ++g2) {
      const int j = wn2 + (g2 << 4) + col;
      const short8 bh = *(const short8*)&Yh[j][(j2 << 5) + (quad << 3)];
      const short8 bl = *(const short8*)&Yl[j][(j2 << 5) + (quad << 3)];
      #pragma unroll
      for (int f2 = 0; f2 < 4; ++f2) {
        acc2[f2][g2] = __builtin_amdgcn_mfma_f32_16x16x32_bf16(aH[f2], bh, acc2[f2][g2], 0, 0, 0);
        acc2[f2][g2] = __builtin_amdgcn_mfma_f32_16x16x32_bf16(aH[f2], bl, acc2[f2][g2], 0, 0, 0);
        acc2[f2][g2] = __builtin_amdgcn_mfma_f32_16x16x32_bf16(aL[f2], bh, acc2[f2][g2], 0, 0, 0);
      }
    }
    __syncthreads();
  }
  const size_t obase = (size_t)b * (size_t)(128 * HW) + ((size_t)cb << 7) + jBase;
  #pragma unroll
  for (int f2 = 0; f2 < 4; ++f2)
    #pragma unroll
    for (int r = 0; r < 4; ++r) {
      const int o = wm2 + (f2 << 4) + (quad << 2) + r;
      #pragma unroll
      for (int g2 = 0; g2 < 2; ++g2) {
        const int j = wn2 + (g2 << 4) + col;
        out[obase + (size_t)o * HW + j] = acc2[f2][g2][r] + b1_s[o];
      }
    }
}

extern "C" void kernel_launch(void* const* d_in, const int* in_sizes, int n_in,
                              void* d_out, int out_size, void* d_ws, size_t ws_size,
                              hipStream_t stream)
{
  const float* x    = (const float*)d_in[0];
  const float* g1   = (const float*)d_in[1];
  const float* be1  = (const float*)d_in[2];
  const float* m1   = (const float*)d_in[3];
  const float* v1   = (const float*)d_in[4];
  const float* wpw0 = (const float*)d_in[5];
  const float* wvp  = (const float*)d_in[6];
  const float* bvp  = (const float*)d_in[7];
  const float* womW = (const float*)d_in[8];
  const float* bom  = (const float*)d_in[9];
  const float* wop  = (const float*)d_in[10];
  const float* g2   = (const float*)d_in[11];
  const float* be2  = (const float*)d_in[12];
  const float* m2   = (const float*)d_in[13];
  const float* v2   = (const float*)d_in[14];
  const float* wpw1 = (const float*)d_in[15];

  char* ws = (char*)d_ws;
  float*  value = (float*) (ws + 0);          // 16 MB (b,s,cg) f32
  float*  omb   = (float*) (ws + 16777216);   //  4 MB (b,s,32) f32
  ushort* samph = (ushort*)(ws + 20971520);   //  8 MB
  ushort* sampl = (ushort*)(ws + 29360128);   //  8 MB
  size_t o = 37748736;
  ushort* W0h = (ushort*)(ws + o); o += 32768;
  ushort* W0l = (ushort*)(ws + o); o += 32768;
  ushort* W1h = (ushort*)(ws + o); o += 32768;
  ushort* W1l = (ushort*)(ws + o); o += 32768;
  ushort* vph = (ushort*)(ws + o); o += 40960;  // 160 x 128 (value 128 + om 32 rows)
  ushort* vpl = (ushort*)(ws + o); o += 40960;
  ushort* oph = (ushort*)(ws + o); o += 32768;
  ushort* opl = (ushort*)(ws + o); o += 32768;
  float*  b0  = (float*)(ws + o);  o += 512;
  float*  b1  = (float*)(ws + o);
  ushort* omh = vph + 128 * 128;
  ushort* oml = vpl + 128 * 128;

  prep<<<34, 256, 0, stream>>>(g1, be1, m1, v1, wpw0, g2, be2, m2, v2, wpw1,
                               wvp, womW, wop,
                               W0h, W0l, b0, W1h, W1l, b1,
                               vph, vpl, oph, opl, omh, oml);
  fused_x_valom<<<dim3(32, 8, 2), 256, 0, stream>>>(x, W0h, W0l, b0, vph, vpl,
                                                    bvp, bom, value, omb);
  dcn_sample<<<dim3(4096), 256, 0, stream>>>(value, omb, samph, sampl);
  fused_op_out<<<dim3(64, 8), 256, 0, stream>>>(samph, sampl, oph, opl,
                                                W1h, W1l, b1, (float*)d_out);
}